// Round 3
// baseline (513.100 us; speedup 1.0000x reference)
//
#include <hip/hip_runtime.h>
#include <math.h>

// Problem constants (match reference)
#define DIM 16777216
#define TAU 0.01f
#define CONSISTENCY_WEIGHT 0.1f
#define SATURATION 5.0f
#define FAST_RATE 0.01f
#define SLOW_RATE 0.001f
#define FAST_DECAY 0.9995f
#define SCHEMA_SPEEDUP 15.0f

constexpr int BLOCK = 256;
constexpr int NBLOCKS = 4096;
constexpr int STRIDE = NBLOCKS * BLOCK;            // 1,048,576 threads
constexpr int ITERS = (DIM / 4) / STRIDE;          // 4 float4s per thread per stream
constexpr int WAVES_PER_BLOCK = BLOCK / 64;

typedef float f4 __attribute__((ext_vector_type(4)));

// Kernel 1: fused elementwise (new_narrative, velocity) + partial reductions.
//
// ROUND 2 CHANGE: round 1's source-order "load all, then compute" was undone
// by the instruction scheduler (VGPR stayed 36 -> loads were sunk back next
// to their uses; ~0.1 loads in flight per wave; 1.9 TB/s). This round pins
// the schedule with __builtin_amdgcn_sched_barrier(0): all ITERS*6 = 24
// float4 loads MUST issue before any consumer. That forces ~24 KB of HBM
// traffic in flight per wave (~100+ VGPRs). Even at the reduced occupancy
// this implies (~12 waves/CU), in-flight bytes per CU (~288 KB) are far
// above the ~9 KB needed to sustain the 6.3 TB/s ceiling.
// Loads plain/cached; stores nontemporal (keeps the output stream from
// evicting the L3-resident inputs — FETCH_SIZE shows L3 currently serves
// half the logical reads; watch FETCH_SIZE to re-test this assumption).
__global__ __launch_bounds__(BLOCK) void ni_main_kernel(
    const float* __restrict__ summary,   // (4, DIM)
    const float* __restrict__ narrative, // (DIM,)
    const float* __restrict__ tonic,     // (DIM,)
    float* __restrict__ out,             // [0,DIM)=new_narrative [DIM,2DIM)=velocity
    float* __restrict__ partials)        // ws: [0,NBLOCKS)=dev2, [NBLOCKS,2*NBLOCKS)=css2
{
    const f4* a0 = (const f4*)(summary);
    const f4* a1 = (const f4*)(summary + (size_t)DIM);
    const f4* a2 = (const f4*)(summary + (size_t)2 * DIM);
    const f4* a3 = (const f4*)(summary + (size_t)3 * DIM);
    const f4* n4 = (const f4*)narrative;
    const f4* t4 = (const f4*)tonic;
    f4* newn = (f4*)out;
    f4* vel  = (f4*)(out + (size_t)DIM);

    const int i0 = blockIdx.x * BLOCK + threadIdx.x;

    // ---- phase 1: issue ALL loads ----
    f4 v0[ITERS], v1[ITERS], v2[ITERS], v3[ITERS], nn[ITERS], tt[ITERS];
    #pragma unroll
    for (int k = 0; k < ITERS; ++k) {
        const int i = i0 + k * STRIDE;
        v0[k] = a0[i];
        v1[k] = a1[i];
        v2[k] = a2[i];
        v3[k] = a3[i];
        nn[k] = n4[i];
        tt[k] = t4[i];
    }

    // Hard scheduling fence: nothing may move across. The 24 loads above are
    // now guaranteed to be issued before any compute/store below.
    __builtin_amdgcn_sched_barrier(0);

    // ---- phase 2: compute + store (vmcnt counts down as we consume) ----
    f4 sum_dev4 = {0.0f, 0.0f, 0.0f, 0.0f};
    f4 sum_css4 = {0.0f, 0.0f, 0.0f, 0.0f};

    #pragma unroll
    for (int k = 0; k < ITERS; ++k) {
        const int i = i0 + k * STRIDE;

        f4 css = 0.25f * ((v0[k] + v1[k]) + (v2[k] + v3[k]));
        f4 dv  = css - nn[k];
        // Exact reference rounding for new_narrative; velocity = nw - nn.
        f4 nw  = nn[k] * (1.0f - TAU) + css * TAU + tt[k];
        f4 ve  = nw - nn[k];

        sum_dev4 += dv * dv;
        sum_css4 += css * css;

        __builtin_nontemporal_store(nw, newn + i);
        __builtin_nontemporal_store(ve, vel + i);
    }

    float sum_dev = (sum_dev4.x + sum_dev4.y) + (sum_dev4.z + sum_dev4.w);
    float sum_css = (sum_css4.x + sum_css4.y) + (sum_css4.z + sum_css4.w);

    // wave(64) shuffle reduce
    #pragma unroll
    for (int off = 32; off > 0; off >>= 1) {
        sum_dev += __shfl_down(sum_dev, off, 64);
        sum_css += __shfl_down(sum_css, off, 64);
    }

    __shared__ float sdev[WAVES_PER_BLOCK];
    __shared__ float scss[WAVES_PER_BLOCK];
    const int lane = threadIdx.x & 63;
    const int wave = threadIdx.x >> 6;
    if (lane == 0) {
        sdev[wave] = sum_dev;
        scss[wave] = sum_css;
    }
    __syncthreads();
    if (threadIdx.x == 0) {
        float d = 0.0f, c = 0.0f;
        #pragma unroll
        for (int w = 0; w < WAVES_PER_BLOCK; ++w) {
            d += sdev[w];
            c += scss[w];
        }
        partials[blockIdx.x] = d;                 // written unconditionally -> poison-safe
        partials[NBLOCKS + blockIdx.x] = c;
    }
}

// Kernel 2: reduce NBLOCKS partials, compute the three scalar outputs.
__global__ __launch_bounds__(1024) void ni_finalize_kernel(
    const float* __restrict__ partials,
    const float* __restrict__ fast_p,
    const float* __restrict__ slow_p,
    float* __restrict__ out)
{
    float sd = 0.0f, sc = 0.0f;
    for (int i = threadIdx.x; i < NBLOCKS; i += 1024) {
        sd += partials[i];
        sc += partials[NBLOCKS + i];
    }
    #pragma unroll
    for (int off = 32; off > 0; off >>= 1) {
        sd += __shfl_down(sd, off, 64);
        sc += __shfl_down(sc, off, 64);
    }
    __shared__ float s1[16];
    __shared__ float s2[16];
    const int lane = threadIdx.x & 63;
    const int wave = threadIdx.x >> 6;
    if (lane == 0) {
        s1[wave] = sd;
        s2[wave] = sc;
    }
    __syncthreads();
    if (threadIdx.x == 0) {
        float d = 0.0f, c = 0.0f;
        #pragma unroll
        for (int w = 0; w < 16; ++w) {
            d += s1[w];
            c += s2[w];
        }
        const float dev_norm = sqrtf(d);
        const float css_norm = sqrtf(c);
        const float consistency_loss = CONSISTENCY_WEIGHT * dev_norm;

        const float fast = *fast_p;
        const float slow = *slow_p;

        const float input_gate = fminf(1.0f, css_norm);
        const float delta_fast = FAST_RATE / (1.0f + fast * SATURATION) * input_gate;
        const float fast_new = fminf(fast * FAST_DECAY + delta_fast, 0.7f);

        const float schema_fit = fminf(fmaxf(1.0f - dev_norm, 0.0f), 1.0f);
        const float schema_multiplier = 1.0f + SCHEMA_SPEEDUP * schema_fit * schema_fit;
        const float delta_slow = SLOW_RATE / (1.0f + slow * SATURATION) * schema_multiplier;
        const float slow_new = fminf(slow + delta_slow, 1.0f);

        const float identity_strength = fminf(fast_new + slow_new, 1.0f);

        out[(size_t)2 * DIM + 0] = consistency_loss;
        out[(size_t)2 * DIM + 1] = identity_strength;
        out[(size_t)2 * DIM + 2] = dev_norm;
    }
}

extern "C" void kernel_launch(void* const* d_in, const int* in_sizes, int n_in,
                              void* d_out, int out_size, void* d_ws, size_t ws_size,
                              hipStream_t stream) {
    const float* summary   = (const float*)d_in[0];  // (4, DIM)
    const float* narrative = (const float*)d_in[1];  // (DIM,)
    const float* tonic     = (const float*)d_in[2];  // (DIM,)
    const float* fast_p    = (const float*)d_in[3];  // scalar
    const float* slow_p    = (const float*)d_in[4];  // scalar
    float* out = (float*)d_out;
    float* partials = (float*)d_ws;                  // needs 2*NBLOCKS*4 = 32 KB

    ni_main_kernel<<<NBLOCKS, BLOCK, 0, stream>>>(summary, narrative, tonic, out, partials);
    ni_finalize_kernel<<<1, 1024, 0, stream>>>(partials, fast_p, slow_p, out);
}

// Round 4
// 482.598 us; speedup vs baseline: 1.0632x; 1.0632x over previous
//
#include <hip/hip_runtime.h>
#include <math.h>

// Problem constants (match reference)
#define DIM 16777216
#define TAU 0.01f
#define CONSISTENCY_WEIGHT 0.1f
#define SATURATION 5.0f
#define FAST_RATE 0.01f
#define SLOW_RATE 0.001f
#define FAST_DECAY 0.9995f
#define SCHEMA_SPEEDUP 15.0f

constexpr int BLOCK = 256;
constexpr int NBLOCKS = 4096;
constexpr int STRIDE = NBLOCKS * BLOCK;            // 1,048,576 threads
constexpr int ITERS = (DIM / 4) / STRIDE;          // 4 float4s per thread per stream
constexpr int WAVES_PER_BLOCK = BLOCK / 64;

typedef float f4 __attribute__((ext_vector_type(4)));

// Kernel 1: fused elementwise (new_narrative, velocity) + partial reductions.
//
// ROUND 3 CHANGE: PLAIN (cached) stores instead of __builtin_nontemporal_store.
// Evidence: four schedule variants all pinned at ~173 us / 1.9 TB/s with
// VALUBusy 3% and occupancy 74% -> waves are resident but blocked in s_waitcnt.
// vmcnt counts stores as well as loads; with ~32 VGPRs the allocator reuses
// store-source registers, so each iteration drains its two stores before the
// next loads issue. NT stores complete at the fabric/HBM controller (us-scale
// under congestion); plain stores commit at the XCD L2 (~200 ns). The store
// drain, not load MLP, is the theory for the 3x gap to the 6.3 TB/s ceiling.
// (R2's forced load-hoist is reverted: it cost occupancy, 74%->38%, -12%.)
__global__ __launch_bounds__(BLOCK) void ni_main_kernel(
    const float* __restrict__ summary,   // (4, DIM)
    const float* __restrict__ narrative, // (DIM,)
    const float* __restrict__ tonic,     // (DIM,)
    float* __restrict__ out,             // [0,DIM)=new_narrative [DIM,2DIM)=velocity
    float* __restrict__ partials)        // ws: [0,NBLOCKS)=dev2, [NBLOCKS,2*NBLOCKS)=css2
{
    const f4* a0 = (const f4*)(summary);
    const f4* a1 = (const f4*)(summary + (size_t)DIM);
    const f4* a2 = (const f4*)(summary + (size_t)2 * DIM);
    const f4* a3 = (const f4*)(summary + (size_t)3 * DIM);
    const f4* n4 = (const f4*)narrative;
    const f4* t4 = (const f4*)tonic;
    f4* newn = (f4*)out;
    f4* vel  = (f4*)(out + (size_t)DIM);

    f4 sum_dev4 = {0.0f, 0.0f, 0.0f, 0.0f};
    f4 sum_css4 = {0.0f, 0.0f, 0.0f, 0.0f};

    const int i0 = blockIdx.x * BLOCK + threadIdx.x;

    #pragma unroll
    for (int k = 0; k < ITERS; ++k) {
        const int i = i0 + k * STRIDE;

        f4 v0 = a0[i];
        f4 v1 = a1[i];
        f4 v2 = a2[i];
        f4 v3 = a3[i];
        f4 nn = n4[i];
        f4 tt = t4[i];

        f4 css = 0.25f * ((v0 + v1) + (v2 + v3));
        f4 dv  = css - nn;
        // Exact reference rounding for new_narrative; velocity = nw - nn.
        f4 nw  = nn * (1.0f - TAU) + css * TAU + tt;
        f4 ve  = nw - nn;

        sum_dev4 += dv * dv;
        sum_css4 += css * css;

        newn[i] = nw;   // plain cached store: commits at L2, fast vmcnt retire
        vel[i]  = ve;
    }

    float sum_dev = (sum_dev4.x + sum_dev4.y) + (sum_dev4.z + sum_dev4.w);
    float sum_css = (sum_css4.x + sum_css4.y) + (sum_css4.z + sum_css4.w);

    // wave(64) shuffle reduce
    #pragma unroll
    for (int off = 32; off > 0; off >>= 1) {
        sum_dev += __shfl_down(sum_dev, off, 64);
        sum_css += __shfl_down(sum_css, off, 64);
    }

    __shared__ float sdev[WAVES_PER_BLOCK];
    __shared__ float scss[WAVES_PER_BLOCK];
    const int lane = threadIdx.x & 63;
    const int wave = threadIdx.x >> 6;
    if (lane == 0) {
        sdev[wave] = sum_dev;
        scss[wave] = sum_css;
    }
    __syncthreads();
    if (threadIdx.x == 0) {
        float d = 0.0f, c = 0.0f;
        #pragma unroll
        for (int w = 0; w < WAVES_PER_BLOCK; ++w) {
            d += sdev[w];
            c += scss[w];
        }
        partials[blockIdx.x] = d;                 // written unconditionally -> poison-safe
        partials[NBLOCKS + blockIdx.x] = c;
    }
}

// Kernel 2: reduce NBLOCKS partials, compute the three scalar outputs.
__global__ __launch_bounds__(1024) void ni_finalize_kernel(
    const float* __restrict__ partials,
    const float* __restrict__ fast_p,
    const float* __restrict__ slow_p,
    float* __restrict__ out)
{
    float sd = 0.0f, sc = 0.0f;
    for (int i = threadIdx.x; i < NBLOCKS; i += 1024) {
        sd += partials[i];
        sc += partials[NBLOCKS + i];
    }
    #pragma unroll
    for (int off = 32; off > 0; off >>= 1) {
        sd += __shfl_down(sd, off, 64);
        sc += __shfl_down(sc, off, 64);
    }
    __shared__ float s1[16];
    __shared__ float s2[16];
    const int lane = threadIdx.x & 63;
    const int wave = threadIdx.x >> 6;
    if (lane == 0) {
        s1[wave] = sd;
        s2[wave] = sc;
    }
    __syncthreads();
    if (threadIdx.x == 0) {
        float d = 0.0f, c = 0.0f;
        #pragma unroll
        for (int w = 0; w < 16; ++w) {
            d += s1[w];
            c += s2[w];
        }
        const float dev_norm = sqrtf(d);
        const float css_norm = sqrtf(c);
        const float consistency_loss = CONSISTENCY_WEIGHT * dev_norm;

        const float fast = *fast_p;
        const float slow = *slow_p;

        const float input_gate = fminf(1.0f, css_norm);
        const float delta_fast = FAST_RATE / (1.0f + fast * SATURATION) * input_gate;
        const float fast_new = fminf(fast * FAST_DECAY + delta_fast, 0.7f);

        const float schema_fit = fminf(fmaxf(1.0f - dev_norm, 0.0f), 1.0f);
        const float schema_multiplier = 1.0f + SCHEMA_SPEEDUP * schema_fit * schema_fit;
        const float delta_slow = SLOW_RATE / (1.0f + slow * SATURATION) * schema_multiplier;
        const float slow_new = fminf(slow + delta_slow, 1.0f);

        const float identity_strength = fminf(fast_new + slow_new, 1.0f);

        out[(size_t)2 * DIM + 0] = consistency_loss;
        out[(size_t)2 * DIM + 1] = identity_strength;
        out[(size_t)2 * DIM + 2] = dev_norm;
    }
}

extern "C" void kernel_launch(void* const* d_in, const int* in_sizes, int n_in,
                              void* d_out, int out_size, void* d_ws, size_t ws_size,
                              hipStream_t stream) {
    const float* summary   = (const float*)d_in[0];  // (4, DIM)
    const float* narrative = (const float*)d_in[1];  // (DIM,)
    const float* tonic     = (const float*)d_in[2];  // (DIM,)
    const float* fast_p    = (const float*)d_in[3];  // scalar
    const float* slow_p    = (const float*)d_in[4];  // scalar
    float* out = (float*)d_out;
    float* partials = (float*)d_ws;                  // needs 2*NBLOCKS*4 = 32 KB

    ni_main_kernel<<<NBLOCKS, BLOCK, 0, stream>>>(summary, narrative, tonic, out, partials);
    ni_finalize_kernel<<<1, 1024, 0, stream>>>(partials, fast_p, slow_p, out);
}